// Round 8
// baseline (237.601 us; speedup 1.0000x reference)
//
#include <hip/hip_runtime.h>
#include <hip/hip_bf16.h>
#include <math.h>

#define NEVENT 1024
#define NSTEP 64
#define NWINDOW 2048
#define NHID 128
#define NG 512
#define WPB 8   // windows per block in cls_k

typedef __attribute__((ext_vector_type(8))) short bf16x8;
typedef __attribute__((ext_vector_type(4))) float f32x4;

__device__ __forceinline__ unsigned short f2bf(float f){
  unsigned int u = __float_as_uint(f);
  return (unsigned short)((u + 0x7FFFu + ((u >> 16) & 1u)) >> 16);
}
__device__ __forceinline__ float sigm(float x){
  return __builtin_amdgcn_rcpf(1.0f + __expf(-x));
}
__device__ __forceinline__ float tanh_f(float x){
  float e = __expf(2.0f * x);
  return 1.0f - 2.0f * __builtin_amdgcn_rcpf(e + 1.0f);
}
// lgkm-only barrier: LDS ordering without draining vmcnt (global ops stay in flight)
__device__ __forceinline__ void lgkm_barrier(){
  asm volatile("s_waitcnt lgkmcnt(0)" ::: "memory");
  __builtin_amdgcn_s_barrier();
}
// async 4B global->LDS (no VGPR destination); lds dest must be wave-uniform base (+lane*4)
__device__ __forceinline__ void gload4(const float* g, float* l){
  __builtin_amdgcn_global_load_lds(
      (const __attribute__((address_space(1))) void*)g,
      (__attribute__((address_space(3))) void*)l, 4, 0, 0);
}
// swizzle byte offset within h tile: spread rows across 16B slots
#define SWZ(row, byte) ((byte) ^ (((row) & 7) << 4))

// merged prep kernel:
//  blocks [0,512):   LDS-tiled transpose qWih0 [512][1024] -> qWqT [1024][512]
//  blocks [512,768): LDS-tiled transpose clsW  [1024][256] -> clsWT [256][1024]
//  blocks [768,960): pack6 (six W [512][128] f32 -> bf16 MFMA B-fragments)
__global__ __launch_bounds__(256)
void prep_k(const float* __restrict__ qWih0, float* __restrict__ qWqT,
            const float* __restrict__ clsW,  float* __restrict__ clsWT,
            const float* __restrict__ s0, const float* __restrict__ s1,
            const float* __restrict__ s2, const float* __restrict__ s3,
            const float* __restrict__ s4, const float* __restrict__ s5,
            unsigned short* __restrict__ dst)
{
  const int b = blockIdx.x;
  if (b < 768){
    const float* in; float* out; int R, C, bb;
    if (b < 512){ in = qWih0; out = qWqT; R = NG;     C = NEVENT; bb = b; }
    else        { in = clsW;  out = clsWT; R = NEVENT; C = 2*NHID; bb = b - 512; }
    __shared__ float tl[32][33];
    const int nbx = C >> 5;
    const int by = bb / nbx, bx = bb - by*nbx;
    const int tx = threadIdx.x & 31, ty = threadIdx.x >> 5;
    #pragma unroll
    for (int k = 0; k < 4; ++k){
      int r = by*32 + ty + k*8;
      tl[ty + k*8][tx] = in[r*C + bx*32 + tx];
    }
    __syncthreads();
    #pragma unroll
    for (int k = 0; k < 4; ++k){
      int r = bx*32 + ty + k*8;               // out row = original col
      out[r*R + by*32 + tx] = tl[tx][ty + k*8];
    }
  } else {
    const int bb = b - 768;
    const int g = bb >> 5;
    const int i = (bb & 31)*256 + threadIdx.x;   // [0, 8192)
    const float* src = (g==0)?s0:(g==1)?s1:(g==2)?s2:(g==3)?s3:(g==4)?s4:s5;
    unsigned short* d = dst + g*65536;
    const int lane = i & 63; const int n = (i >> 6) & 31; const int kt = i >> 11;
    const int col = 16*n + (lane & 15);
    const int k0  = 32*kt + 8*(lane >> 4);
    #pragma unroll
    for (int j = 0; j < 8; ++j)
      d[i*8 + j] = f2bf(src[col*128 + k0 + j]);
  }
}

// R17: role-split (waves 0-7 = L1/phase-C, 8-15 = L0/phase-A, one lgkm barrier
// per step) with quant-L0 gathers routed GLOBAL->LDS via global_load_lds (zero
// VGPR destinations). Per interval: issue 8 gathers (q0,q1 of s_{t+2}) ->
// kt0/kt1 MFMAs -> vmcnt(4) -> read+zr01 -> issue 8 (q2,q3) into same slots ->
// kt2/kt3 -> acts -> vmcnt(0) -> zr23. Token prefetch (s_{t+3}) sits between
// the batches in the vmcnt FIFO (fenced). Bit-exact vs R15: zr accumulates the
// same values in the same q-major order, one interval earlier; acc-init reads
// the same zr state (kt0 MFMA takes zr as C-in). sAll removed from LDS
// (register token prefetch). LDS = 128K wih1 + 16K h + 16K gbuf = 163840.
// Spill tripwire: WRITE ~2048KB / FETCH ~12.5MB. absmax must stay 1.9531e-3.
__global__ __launch_bounds__(1024) __attribute__((amdgpu_waves_per_eu(4, 4)))
void lstm_fused_k(const int* __restrict__ seqtok,
    const float* __restrict__ sWih0,
    const float* __restrict__ sb0i, const float* __restrict__ sb0h,
    const float* __restrict__ sb1i, const float* __restrict__ sb1h,
    const float* __restrict__ qb0i, const float* __restrict__ qb0h,
    const float* __restrict__ qb1i, const float* __restrict__ qb1h,
    const unsigned short* __restrict__ pWhh0_s, const unsigned short* __restrict__ pWih1_s,
    const unsigned short* __restrict__ pWhh1_s,
    const unsigned short* __restrict__ pWhh0_q, const unsigned short* __restrict__ pWih1_q,
    const unsigned short* __restrict__ pWhh1_q,
    const float* __restrict__ qWqT,    // [1024][512]
    float* __restrict__ hseq, float* __restrict__ hq)
{
  __shared__ uint4 wih1[8192];                                            // 128 KB
  __shared__ __attribute__((aligned(16))) unsigned short h0buf[2][2048];  // 8 KB
  __shared__ __attribute__((aligned(16))) unsigned short h1buf[2][2048];  // 8 KB
  __shared__ float gbuf[8][8][64];                                        // 16 KB (quant-L0 only)

  const int tid  = threadIdx.x;
  const int lane = tid & 63;
  const int w    = tid >> 6;            // wave id 0..15
  const bool quant = (blockIdx.x >= 128);
  const int blk  = quant ? (int)blockIdx.x - 128 : (int)blockIdx.x;
  const int w0   = blk * 16;

  // ---- prologue staging (all 16 waves): wih1 + h zero ----
  const uint4* wsrc = (const uint4*)(quant ? pWih1_q : pWih1_s);
  for (int i = tid; i < 8192; i += 1024) wih1[i] = wsrc[i];
  for (int i = tid; i < 2048; i += 1024){ h0buf[0][i] = 0; h1buf[0][i] = 0; }

  const int rbase = 4*(lane >> 4);         // window row base (D-layout)
  char* const h0base = (char*)h0buf;
  char* const h1base = (char*)h1buf;

  __syncthreads();   // barrier #0: staged data ready

  if (w < 8){
    // ================= L1 role: layer-1, phase C(t) =================
    const int nw   = w;
    const int jcol = 16*nw + (lane & 15);
    const float* b1i = quant ? qb1i : sb1i; const float* b1h = quant ? qb1h : sb1h;
    f32x4 b1v[4];
    #pragma unroll
    for (int q = 0; q < 4; ++q){
      int col = 128*q + jcol; float b = b1i[col] + b1h[col];
      f32x4 v; v[0]=b; v[1]=b; v[2]=b; v[3]=b; b1v[q] = v;
    }
    const unsigned short* p1 = quant ? pWhh1_q : pWhh1_s;
    bf16x8 whh1f[4][4];
    #pragma unroll
    for (int q = 0; q < 4; ++q)
      #pragma unroll
      for (int kt = 0; kt < 4; ++kt)
        whh1f[q][kt] = *(const bf16x8*)(p1 + ((kt*32 + 8*q + nw)*64 + lane)*8);
    float c1[4] = {0,0,0,0};
    float* const houtp = quant ? hq : hseq;

    lgkm_barrier();    // barrier #1: h0[0] ready

    for (int t = 0; t < NSTEP-1; ++t){
      char* h0rd = h0base + ((t+1)&1)*4096;   // h0[t]
      char* h1rd = h1base + ((t  )&1)*4096;   // h1[t-1]
      char* h1wr = h1base + ((t+1)&1)*4096;   // h1[t]
      const int row = lane & 15;
      f32x4 acc[4];
      {  // kt = 0, C-in = b1v
        int off = SWZ(row, row*256 + 0*64 + (lane>>4)*16);
        const bf16x8 a0 = *(const bf16x8*)(h0rd + off);
        const bf16x8 a1 = *(const bf16x8*)(h1rd + off);
        #pragma unroll
        for (int q = 0; q < 4; ++q){
          const bf16x8 wi = *(const bf16x8*)((const char*)wih1 + ((0*32 + 8*q + nw)*64 + lane)*16);
          acc[q] = __builtin_amdgcn_mfma_f32_16x16x32_bf16(a0, wi,          b1v[q], 0, 0, 0);
          acc[q] = __builtin_amdgcn_mfma_f32_16x16x32_bf16(a1, whh1f[q][0], acc[q], 0, 0, 0);
        }
      }
      #pragma unroll
      for (int kt = 1; kt < 4; ++kt){
        int off = SWZ(row, row*256 + kt*64 + (lane>>4)*16);
        const bf16x8 a0 = *(const bf16x8*)(h0rd + off);
        const bf16x8 a1 = *(const bf16x8*)(h1rd + off);
        #pragma unroll
        for (int q = 0; q < 4; ++q){
          const bf16x8 wi = *(const bf16x8*)((const char*)wih1 + ((kt*32 + 8*q + nw)*64 + lane)*16);
          acc[q] = __builtin_amdgcn_mfma_f32_16x16x32_bf16(a0, wi,           acc[q], 0, 0, 0);
          acc[q] = __builtin_amdgcn_mfma_f32_16x16x32_bf16(a1, whh1f[q][kt], acc[q], 0, 0, 0);
        }
      }
      #pragma unroll
      for (int r = 0; r < 4; ++r){
        float iv = sigm(acc[0][r]), fv = sigm(acc[1][r]);
        float gv = tanh_f(acc[2][r]), ov = sigm(acc[3][r]);
        c1[r] = fv*c1[r] + iv*gv;
        float h = ov * tanh_f(c1[r]);
        int rw = rbase + r;
        *(unsigned short*)(h1wr + SWZ(rw, rw*256 + jcol*2)) = f2bf(h);
      }
      lgkm_barrier();
    }

    // ---- epilogue C(63): write global output only ----
    {
      char* h0rd = h0base + 0*4096;           // h0[63]
      char* h1rd = h1base + 1*4096;           // h1[62]
      const int row = lane & 15;
      f32x4 acc[4];
      {
        int off = SWZ(row, row*256 + 0*64 + (lane>>4)*16);
        const bf16x8 a0 = *(const bf16x8*)(h0rd + off);
        const bf16x8 a1 = *(const bf16x8*)(h1rd + off);
        #pragma unroll
        for (int q = 0; q < 4; ++q){
          const bf16x8 wi = *(const bf16x8*)((const char*)wih1 + ((0*32 + 8*q + nw)*64 + lane)*16);
          acc[q] = __builtin_amdgcn_mfma_f32_16x16x32_bf16(a0, wi,          b1v[q], 0, 0, 0);
          acc[q] = __builtin_amdgcn_mfma_f32_16x16x32_bf16(a1, whh1f[q][0], acc[q], 0, 0, 0);
        }
      }
      #pragma unroll
      for (int kt = 1; kt < 4; ++kt){
        int off = SWZ(row, row*256 + kt*64 + (lane>>4)*16);
        const bf16x8 a0 = *(const bf16x8*)(h0rd + off);
        const bf16x8 a1 = *(const bf16x8*)(h1rd + off);
        #pragma unroll
        for (int q = 0; q < 4; ++q){
          const bf16x8 wi = *(const bf16x8*)((const char*)wih1 + ((kt*32 + 8*q + nw)*64 + lane)*16);
          acc[q] = __builtin_amdgcn_mfma_f32_16x16x32_bf16(a0, wi,           acc[q], 0, 0, 0);
          acc[q] = __builtin_amdgcn_mfma_f32_16x16x32_bf16(a1, whh1f[q][kt], acc[q], 0, 0, 0);
        }
      }
      #pragma unroll
      for (int r = 0; r < 4; ++r){
        float iv = sigm(acc[0][r]), fv = sigm(acc[1][r]);
        float gv = tanh_f(acc[2][r]), ov = sigm(acc[3][r]);
        c1[r] = fv*c1[r] + iv*gv;
        float h = ov * tanh_f(c1[r]);
        int rw = rbase + r;
        houtp[(w0 + rw)*128 + jcol] = h;
      }
    }
  } else {
    // ================= L0 role: layer-0, phase A(t+1) =================
    const int nw   = w - 8;
    const int jcol = 16*nw + (lane & 15);
    const float* b0i = quant ? qb0i : sb0i; const float* b0h = quant ? qb0h : sb0h;
    float b0c[4];
    #pragma unroll
    for (int q = 0; q < 4; ++q){
      int col = 128*q + jcol;
      b0c[q] = b0i[col] + b0h[col];
    }
    const unsigned short* p0 = quant ? pWhh0_q : pWhh0_s;
    bf16x8 whh0f[4][4];
    #pragma unroll
    for (int q = 0; q < 4; ++q)
      #pragma unroll
      for (int kt = 0; kt < 4; ++kt)
        whh0f[q][kt] = *(const bf16x8*)(p0 + ((kt*32 + 8*q + nw)*64 + lane)*8);

    float c0[4] = {0,0,0,0};
    const int* const tp = seqtok + (w0 + rbase)*64;   // tokens: row r at tp[64*r + t]

    if (quant){
      const float* const gq = qWqT + jcol;            // per-lane gather base
      float* const gslot = &gbuf[nw][0][0];           // wave-uniform LDS base
      f32x4 zr[4];                                    // b0 + cumulative gather
      #pragma unroll
      for (int q = 0; q < 4; ++q){ f32x4 v; v[0]=b0c[q]; v[1]=b0c[q]; v[2]=b0c[q]; v[3]=b0c[q]; zr[q]=v; }

      // ---- A(0): in-reg gather g(s_0); gates(0); then zr += g(s_1); prime tokens s_2 ----
      {
        int u0 = tp[0], u1 = tp[64], u2 = tp[128], u3 = tp[192];    // s_0
        float pf[4][4];
        #pragma unroll
        for (int q = 0; q < 4; ++q){
          pf[q][0] = gq[u0*512 + 128*q]; pf[q][1] = gq[u1*512 + 128*q];
          pf[q][2] = gq[u2*512 + 128*q]; pf[q][3] = gq[u3*512 + 128*q];
        }
        float g0[4][4];
        #pragma unroll
        for (int q = 0; q < 4; ++q)
          #pragma unroll
          for (int r = 0; r < 4; ++r){ zr[q][r] += pf[q][r]; g0[q][r] = zr[q][r]; }
        #pragma unroll
        for (int r = 0; r < 4; ++r){
          float iv = sigm(g0[0][r]);
          float gv = tanh_f(g0[2][r]);
          float ov = sigm(g0[3][r]);
          c0[r] = iv * gv;                 // f*c_prev = 0
          float h = ov * tanh_f(c0[r]);
          int rw = rbase + r;
          *(unsigned short*)(h0base + 4096 + SWZ(rw, rw*256 + jcol*2)) = f2bf(h);  // h0[0] -> buf 1
        }
        // zr += g(s_1) (same q-major order)
        int v0 = tp[1], v1 = tp[65], v2 = tp[129], v3 = tp[193];    // s_1
        #pragma unroll
        for (int q = 0; q < 4; ++q){
          pf[q][0] = gq[v0*512 + 128*q]; pf[q][1] = gq[v1*512 + 128*q];
          pf[q][2] = gq[v2*512 + 128*q]; pf[q][3] = gq[v3*512 + 128*q];
        }
        #pragma unroll
        for (int q = 0; q < 4; ++q)
          #pragma unroll
          for (int r = 0; r < 4; ++r) zr[q][r] += pf[q][r];
      }
      int tok0 = tp[2], tok1 = tp[66], tok2 = tp[130], tok3 = tp[194];  // s_2
      lgkm_barrier();    // barrier #1

      for (int t = 0; t < NSTEP-1; ++t){
        char* h0rd = h0base + ((t+1)&1)*4096;   // h0[t]
        char* h0wr = h0base + ((t  )&1)*4096;   // h0[t+1]
        const int row = lane & 15;
        // gather bases for s_{t+2} (tokens from last interval's prefetch)
        const float* ga0 = gq + tok0*512;
        const float* ga1 = gq + tok1*512;
        const float* ga2 = gq + tok2*512;
        const float* ga3 = gq + tok3*512;
        // batch q0,q1 -> slots 0..7 (zero VGPR dests)
        gload4(ga0,       gslot + 0*64);
        gload4(ga1,       gslot + 1*64);
        gload4(ga2,       gslot + 2*64);
        gload4(ga3,       gslot + 3*64);
        gload4(ga0 + 128, gslot + 4*64);
        gload4(ga1 + 128, gslot + 5*64);
        gload4(ga2 + 128, gslot + 6*64);
        gload4(ga3 + 128, gslot + 7*64);
        asm volatile("" ::: "memory");          // pin token loads AFTER the 8 gathers (vmcnt FIFO)
        int t3 = (t+3 < NSTEP) ? t+3 : NSTEP-1;
        tok0 = tp[t3]; tok1 = tp[64+t3]; tok2 = tp[128+t3]; tok3 = tp[192+t3];
        // MFMA kt0 (C-in = zr), kt1
        f32x4 acc[4];
        {
          int off = SWZ(row, row*256 + 0*64 + (lane>>4)*16);
          const bf16x8 a0 = *(const bf16x8*)(h0rd + off);
          #pragma unroll
          for (int q = 0; q < 4; ++q)
            acc[q] = __builtin_amdgcn_mfma_f32_16x16x32_bf16(a0, whh0f[q][0], zr[q], 0, 0, 0);
        }
        {
          int off = SWZ(row, row*256 + 1*64 + (lane>>4)*16);
          const bf16x8 a0 = *(const bf16x8*)(h0rd + off);
          #pragma unroll
          for (int q = 0; q < 4; ++q)
            acc[q] = __builtin_amdgcn_mfma_f32_16x16x32_bf16(a0, whh0f[q][1], acc[q], 0, 0, 0);
        }
        // consume batch q0,q1 (4 token loads remain in flight)
        asm volatile("s_waitcnt vmcnt(4)" ::: "memory");
        {
          float g0 = gslot[0*64+lane], g1 = gslot[1*64+lane], g2 = gslot[2*64+lane], g3 = gslot[3*64+lane];
          float g4 = gslot[4*64+lane], g5 = gslot[5*64+lane], g6 = gslot[6*64+lane], g7 = gslot[7*64+lane];
          zr[0][0] += g0; zr[0][1] += g1; zr[0][2] += g2; zr[0][3] += g3;
          zr[1][0] += g4; zr[1][1] += g5; zr[1][2] += g6; zr[1][3] += g7;
        }
        asm volatile("s_waitcnt lgkmcnt(0)" ::: "memory");   // reads done before slot reuse
        // batch q2,q3 -> same slots
        gload4(ga0 + 256, gslot + 0*64);
        gload4(ga1 + 256, gslot + 1*64);
        gload4(ga2 + 256, gslot + 2*64);
        gload4(ga3 + 256, gslot + 3*64);
        gload4(ga0 + 384, gslot + 4*64);
        gload4(ga1 + 384, gslot + 5*64);
        gload4(ga2 + 384, gslot + 6*64);
        gload4(ga3 + 384, gslot + 7*64);
        // MFMA kt2, kt3
        {
          int off = SWZ(row, row*256 + 2*64 + (lane>>4)*16);
          const bf16x8 a0 = *(const bf16x8*)(h0rd + off);
          #pragma unroll
          for (int q = 0; q < 4; ++q)
            acc[q] = __builtin_amdgcn_mfma_f32_16x16x32_bf16(a0, whh0f[q][2], acc[q], 0, 0, 0);
        }
        {
          int off = SWZ(row, row*256 + 3*64 + (lane>>4)*16);
          const bf16x8 a0 = *(const bf16x8*)(h0rd + off);
          #pragma unroll
          for (int q = 0; q < 4; ++q)
            acc[q] = __builtin_amdgcn_mfma_f32_16x16x32_bf16(a0, whh0f[q][3], acc[q], 0, 0, 0);
        }
        // activations + h0 write
        #pragma unroll
        for (int r = 0; r < 4; ++r){
          float iv = sigm(acc[0][r]), fv = sigm(acc[1][r]);
          float gv = tanh_f(acc[2][r]), ov = sigm(acc[3][r]);
          c0[r] = fv*c0[r] + iv*gv;
          float h = ov * tanh_f(c0[r]);
          int rw = rbase + r;
          *(unsigned short*)(h0wr + SWZ(rw, rw*256 + jcol*2)) = f2bf(h);
        }
        // consume batch q2,q3 (drains tokens too -> ready next interval)
        asm volatile("s_waitcnt vmcnt(0)" ::: "memory");
        {
          float g0 = gslot[0*64+lane], g1 = gslot[1*64+lane], g2 = gslot[2*64+lane], g3 = gslot[3*64+lane];
          float g4 = gslot[4*64+lane], g5 = gslot[5*64+lane], g6 = gslot[6*64+lane], g7 = gslot[7*64+lane];
          zr[2][0] += g0; zr[2][1] += g1; zr[2][2] += g2; zr[2][3] += g3;
          zr[3][0] += g4; zr[3][1] += g5; zr[3][2] += g6; zr[3][3] += g7;
        }
        lgkm_barrier();
      }
    } else {
      // ---- seq arm: scalar token input; register token prefetch ----
      float wc[4];
      #pragma unroll
      for (int q = 0; q < 4; ++q) wc[q] = sWih0[128*q + jcol];
      int tok0, tok1, tok2, tok3;
      // A(0)
      {
        int u0 = tp[0], u1 = tp[64], u2 = tp[128], u3 = tp[192];
        float sv[4] = {(float)u0, (float)u1, (float)u2, (float)u3};
        float g0[4][4];
        #pragma unroll
        for (int r = 0; r < 4; ++r)
          #pragma unroll
          for (int q = 0; q < 4; ++q) g0[q][r] = fmaf(sv[r], wc[q], b0c[q]);
        #pragma unroll
        for (int r = 0; r < 4; ++r){
          float iv = sigm(g0[0][r]);
          float gv = tanh_f(g0[2][r]);
          float ov = sigm(g0[3][r]);
          c0[r] = iv * gv;
          float h = ov * tanh_f(c0[r]);
          int rw = rbase + r;
          *(unsigned short*)(h0base + 4096 + SWZ(rw, rw*256 + jcol*2)) = f2bf(h);  // h0[0] -> buf 1
        }
        tok0 = tp[1]; tok1 = tp[65]; tok2 = tp[129]; tok3 = tp[193];   // s_1
      }
      lgkm_barrier();    // barrier #1

      for (int t = 0; t < NSTEP-1; ++t){
        char* h0rd = h0base + ((t+1)&1)*4096;   // h0[t]
        char* h0wr = h0base + ((t  )&1)*4096;   // h0[t+1]
        const int row = lane & 15;
        float sv[4] = {(float)tok0, (float)tok1, (float)tok2, (float)tok3};
        int t2 = (t+2 < NSTEP) ? t+2 : NSTEP-1;
        tok0 = tp[t2]; tok1 = tp[64+t2]; tok2 = tp[128+t2]; tok3 = tp[192+t2];
        f32x4 acc[4];
        #pragma unroll
        for (int q = 0; q < 4; ++q){
          f32x4 a;
          #pragma unroll
          for (int r = 0; r < 4; ++r) a[r] = fmaf(sv[r], wc[q], b0c[q]);
          acc[q] = a;
        }
        #pragma unroll
        for (int kt = 0; kt < 4; ++kt){
          int off = SWZ(row, row*256 + kt*64 + (lane>>4)*16);
          const bf16x8 a0 = *(const bf16x8*)(h0rd + off);
          #pragma unroll
          for (int q = 0; q < 4; ++q)
            acc[q] = __builtin_amdgcn_mfma_f32_16x16x32_bf16(a0, whh0f[q][kt], acc[q], 0, 0, 0);
        }
        #pragma unroll
        for (int r = 0; r < 4; ++r){
          float iv = sigm(acc[0][r]), fv = sigm(acc[1][r]);
          float gv = tanh_f(acc[2][r]), ov = sigm(acc[3][r]);
          c0[r] = fv*c0[r] + iv*gv;
          float h = ov * tanh_f(c0[r]);
          int rw = rbase + r;
          *(unsigned short*)(h0wr + SWZ(rw, rw*256 + jcol*2)) = f2bf(h);
        }
        lgkm_barrier();
      }
    }
    // L0 done: 64 barriers executed, matching L1's count before its epilogue.
  }
}

// out[b][e] = dot(hcat[b], clsW[e]) + clsb[e]; clsWT is [256][1024]
__global__ __launch_bounds__(256, 4)
void cls_k(const float* __restrict__ hseq, const float* __restrict__ hq,
           const float* __restrict__ clsWT, const float* __restrict__ clsb,
           float* __restrict__ out)
{
  __shared__ float hcat[WPB][2*NHID];
  const int tid = threadIdx.x;
  const int w0 = blockIdx.x * WPB;
  for (int i = tid; i < WPB*2*NHID; i += 256){
    int w = i >> 8; int j = i & (2*NHID-1);
    hcat[w][j] = (j < NHID) ? hseq[(w0+w)*NHID + j] : hq[(w0+w)*NHID + (j - NHID)];
  }
  __syncthreads();
  float acc[4][WPB];
  #pragma unroll
  for (int p=0;p<4;++p)
    #pragma unroll
    for (int w=0;w<WPB;++w) acc[p][w] = 0.0f;
  for (int j = 0; j < 2*NHID; ++j){
    float wv0 = clsWT[j*NEVENT + tid];
    float wv1 = clsWT[j*NEVENT + tid + 256];
    float wv2 = clsWT[j*NEVENT + tid + 512];
    float wv3 = clsWT[j*NEVENT + tid + 768];
    #pragma unroll
    for (int w=0; w<WPB; ++w){
      float hv = hcat[w][j];
      acc[0][w] = fmaf(hv, wv0, acc[0][w]);
      acc[1][w] = fmaf(hv, wv1, acc[1][w]);
      acc[2][w] = fmaf(hv, wv2, acc[2][w]);
      acc[3][w] = fmaf(hv, wv3, acc[3][w]);
    }
  }
  #pragma unroll
  for (int p=0;p<4;++p){
    float bb = clsb[tid + p*256];
    #pragma unroll
    for (int w=0;w<WPB;++w)
      out[(w0+w)*NEVENT + tid + p*256] = acc[p][w] + bb;
  }
}

extern "C" void kernel_launch(void* const* d_in, const int* in_sizes, int n_in,
                              void* d_out, int out_size, void* d_ws, size_t ws_size,
                              hipStream_t stream) {
  const int*   seqtok = (const int*)  d_in[0];
  const float* sWih0  = (const float*)d_in[1];
  const float* sWhh0  = (const float*)d_in[2];
  const float* sb0i   = (const float*)d_in[3];
  const float* sb0h   = (const float*)d_in[4];
  const float* sWih1  = (const float*)d_in[5];
  const float* sWhh1  = (const float*)d_in[6];
  const float* sb1i   = (const float*)d_in[7];
  const float* sb1h   = (const float*)d_in[8];
  const float* qWih0  = (const float*)d_in[9];
  const float* qWhh0  = (const float*)d_in[10];
  const float* qb0i   = (const float*)d_in[11];
  const float* qb0h   = (const float*)d_in[12];
  const float* qWih1  = (const float*)d_in[13];
  const float* qWhh1  = (const float*)d_in[14];
  const float* qb1i   = (const float*)d_in[15];
  const float* qb1h   = (const float*)d_in[16];
  const float* clsW   = (const float*)d_in[17];
  const float* clsb   = (const float*)d_in[18];

  float* ws = (float*)d_ws;
  float* qWqT  = ws;                    // 1024*512 = 524288
  float* clsWT = ws + 524288;           // 256*1024 = 262144
  float* hseq  = ws + 786432;           // 2048*128 = 262144
  float* hq    = ws + 1048576;          // 262144
  unsigned short* pk = (unsigned short*)(ws + 1310720);
  unsigned short* pWhh0_s = pk;             // 6 matrices x 65536 ushorts
  unsigned short* pWih1_s = pk + 65536;
  unsigned short* pWhh1_s = pk + 131072;
  unsigned short* pWhh0_q = pk + 196608;
  unsigned short* pWih1_q = pk + 262144;
  unsigned short* pWhh1_q = pk + 327680;

  prep_k<<<960, 256, 0, stream>>>(qWih0, qWqT, clsW, clsWT,
      sWhh0, sWih1, sWhh1, qWhh0, qWih1, qWhh1, pk);

  lstm_fused_k<<<256, 1024, 0, stream>>>(seqtok, sWih0,
      sb0i, sb0h, sb1i, sb1h, qb0i, qb0h, qb1i, qb1h,
      pWhh0_s, pWih1_s, pWhh1_s, pWhh0_q, pWih1_q, pWhh1_q,
      qWqT, hseq, hq);

  cls_k<<<NWINDOW/WPB, 256, 0, stream>>>(hseq, hq, clsWT, clsb, (float*)d_out);
}